// Round 6
// baseline (150.624 us; speedup 1.0000x reference)
//
#include <hip/hip_runtime.h>

#define BATCH 16
#define TOK   4096
#define DIM   768
#define SMAX  128
#define BM    8     // rows per MLP block

__device__ __forceinline__ int lower_bound_i(const int* __restrict__ a, int n, int v) {
    int lo = 0, hi = n;
    while (lo < hi) {
        int m = (lo + hi) >> 1;
        if (a[m] < v) lo = m + 1; else hi = m;
    }
    return lo;
}

__device__ __forceinline__ float f4get(const float4& v, int k) {
    switch (k) {
        case 0: return v.x;
        case 1: return v.y;
        case 2: return v.z;
        default: return v.w;
    }
}

__device__ __forceinline__ void f4acc(float4& a, const float4& v) {
    a.x += v.x; a.y += v.y; a.z += v.z; a.w += v.w;
}

// Kernel A: per-(b,s) segment sum over contiguous sorted token span.
// (unchanged from round 4 for attribution)
__global__ __launch_bounds__(192)
void segsum_kernel(const float* __restrict__ hidden,
                   const int* __restrict__ seg,
                   float* __restrict__ sent) {
    const int s = blockIdx.x;
    const int b = blockIdx.y;
    const int tid = threadIdx.x;

    const int* srow = seg + b * TOK;
    const int lo = lower_bound_i(srow, TOK, s);
    const int hi = lower_bound_i(srow, TOK, s + 1);

    const float4* __restrict__ hp =
        reinterpret_cast<const float4*>(hidden + (size_t)b * TOK * DIM) + tid;

    float4 acc = make_float4(0.f, 0.f, 0.f, 0.f);
    int t = lo;

    for (; t + 16 <= hi; t += 16) {
        float4 v[16];
        #pragma unroll
        for (int u = 0; u < 16; ++u)
            v[u] = hp[(size_t)(t + u) * (DIM / 4)];
        #pragma unroll
        for (int u = 0; u < 16; ++u)
            f4acc(acc, v[u]);
    }
    for (; t + 4 <= hi; t += 4) {
        float4 v[4];
        #pragma unroll
        for (int u = 0; u < 4; ++u)
            v[u] = hp[(size_t)(t + u) * (DIM / 4)];
        #pragma unroll
        for (int u = 0; u < 4; ++u)
            f4acc(acc, v[u]);
    }
    for (; t < hi; ++t)
        f4acc(acc, hp[(size_t)t * (DIM / 4)]);

    float4* outp = reinterpret_cast<float4*>(sent + (size_t)(b * SMAX + s) * DIM);
    outp[tid] = acc;
}

// Kernel B: fused MLP head, BM=8 rows per block, 512 threads (8 waves = 2/SIMD).
// Each thread: layer1 -> 2 rows x 3 cols; layer2 -> 2 rows x 1 col.
__global__ __launch_bounds__(512)
void mlp_kernel(const float* __restrict__ sent,
                const float* __restrict__ W1, const float* __restrict__ b1,
                const float* __restrict__ W2, const float* __restrict__ b2,
                const float* __restrict__ W3, const float* __restrict__ b3,
                float* __restrict__ out) {
    __shared__ float A[BM][DIM];     // 24 KB
    __shared__ float X1[BM][384];    // 12 KB
    __shared__ float X2[BM][128];    // 4 KB

    const int tid = threadIdx.x;
    const int row0 = blockIdx.x * BM;

    // Stage A tile: 1536 float4 over 512 threads -> 3 each
    {
        const float4* src = reinterpret_cast<const float4*>(sent + (size_t)row0 * DIM);
        float4* dst = reinterpret_cast<float4*>(&A[0][0]);
        #pragma unroll
        for (int i = 0; i < 3; ++i)
            dst[tid + i * 512] = src[tid + i * 512];
    }
    __syncthreads();

    const int c1 = tid & 127;   // column within 128-group
    const int g  = tid >> 7;    // 0..3 -> rows 2g, 2g+1
    const int r0 = g * 2;

    // ---- layer 1: acc[2 rows][3 cols] over k=0..767 ----
    float acc[2][3];
    #pragma unroll
    for (int i = 0; i < 2; ++i)
        #pragma unroll
        for (int j = 0; j < 3; ++j) acc[i][j] = 0.f;

    #pragma unroll 4
    for (int k = 0; k < DIM; k += 4) {
        float4 a0 = *reinterpret_cast<const float4*>(&A[r0][k]);
        float4 a1 = *reinterpret_cast<const float4*>(&A[r0 + 1][k]);
        #pragma unroll
        for (int kk = 0; kk < 4; ++kk) {
            const float w0 = W1[(k + kk) * 384 + c1];
            const float w1 = W1[(k + kk) * 384 + c1 + 128];
            const float w2 = W1[(k + kk) * 384 + c1 + 256];
            const float a0v = f4get(a0, kk);
            const float a1v = f4get(a1, kk);
            acc[0][0] = fmaf(a0v, w0, acc[0][0]);
            acc[0][1] = fmaf(a0v, w1, acc[0][1]);
            acc[0][2] = fmaf(a0v, w2, acc[0][2]);
            acc[1][0] = fmaf(a1v, w0, acc[1][0]);
            acc[1][1] = fmaf(a1v, w1, acc[1][1]);
            acc[1][2] = fmaf(a1v, w2, acc[1][2]);
        }
    }
    #pragma unroll
    for (int j = 0; j < 3; ++j) {
        const float bb = b1[c1 + j * 128];
        #pragma unroll
        for (int i = 0; i < 2; ++i) {
            const float v = acc[i][j] + bb;
            X1[r0 + i][c1 + j * 128] = v > 0.f ? v : 0.f;
        }
    }
    __syncthreads();

    // ---- layer 2: 2 rows x col c1 over k=0..383 ----
    float acc2[2] = {0.f, 0.f};
    #pragma unroll 4
    for (int k = 0; k < 384; k += 4) {
        float4 x0 = *reinterpret_cast<const float4*>(&X1[r0][k]);
        float4 x1 = *reinterpret_cast<const float4*>(&X1[r0 + 1][k]);
        #pragma unroll
        for (int kk = 0; kk < 4; ++kk) {
            const float w = W2[(k + kk) * 128 + c1];
            acc2[0] = fmaf(f4get(x0, kk), w, acc2[0]);
            acc2[1] = fmaf(f4get(x1, kk), w, acc2[1]);
        }
    }
    {
        const float bb = b2[c1];
        #pragma unroll
        for (int i = 0; i < 2; ++i) {
            const float v = acc2[i] + bb;
            X2[r0 + i][c1] = v > 0.f ? v : 0.f;
        }
    }
    __syncthreads();

    // ---- layer 3: BM*2 = 16 outputs ----
    if (tid < BM * 2) {
        const int r = tid >> 1;
        const int c = tid & 1;
        float sacc = 0.f;
        #pragma unroll 8
        for (int k = 0; k < 128; ++k)
            sacc = fmaf(X2[r][k], W3[k * 2 + c], sacc);
        out[(row0 + r) * 2 + c] = sacc + b3[c];
    }
}

extern "C" void kernel_launch(void* const* d_in, const int* in_sizes, int n_in,
                              void* d_out, int out_size, void* d_ws, size_t ws_size,
                              hipStream_t stream) {
    const float* hidden = (const float*)d_in[0];
    const int*   seg    = (const int*)d_in[1];
    const float* W1     = (const float*)d_in[2];
    const float* b1     = (const float*)d_in[3];
    const float* W2     = (const float*)d_in[4];
    const float* b2     = (const float*)d_in[5];
    const float* W3     = (const float*)d_in[6];
    const float* b3     = (const float*)d_in[7];
    float* out  = (float*)d_out;
    float* sent = (float*)d_ws;  // BATCH*SMAX*DIM floats = 6 MB

    segsum_kernel<<<dim3(SMAX, BATCH), 192, 0, stream>>>(hidden, seg, sent);
    mlp_kernel<<<(BATCH * SMAX) / BM, 512, 0, stream>>>(sent, W1, b1, W2, b2, W3, b3, out);
}